// Round 8
// baseline (650.315 us; speedup 1.0000x reference)
//
#include <hip/hip_runtime.h>

#define N_NODES 100000
#define N_EDGES 1600000
#define NBUCK   ((N_NODES + 127) / 128)   // 782 buckets of 128 rows
// IN_DIM=512, HID_DIM=128, OUT_DIM=64

typedef __attribute__((ext_vector_type(8))) short bf16x8;
typedef __attribute__((ext_vector_type(4))) float f32x4;

__device__ __forceinline__ unsigned short f2bf(float f) {
    unsigned int u = __builtin_bit_cast(unsigned int, f);
    u = (u + 0x7FFFu + ((u >> 16) & 1u)) >> 16;   // RNE
    return (unsigned short)u;
}
__device__ __forceinline__ float bfu2f(unsigned short u) {
    return __builtin_bit_cast(float, (unsigned int)u << 16);
}

// Raw barrier: waits LDS ops only — global prefetch loads stay in flight.
__device__ __forceinline__ void block_barrier() {
    asm volatile("s_waitcnt lgkmcnt(0)" ::: "memory");
    __builtin_amdgcn_sched_barrier(0);
    __builtin_amdgcn_s_barrier();
    __builtin_amdgcn_sched_barrier(0);
}

// ---------------------------------------------------------------------------
// prep: W0[512][128]->W0t[128][512] bf16, W1[128][64]->W1t[64][128] bf16,
// deg[] = 0.  One launch.
// ---------------------------------------------------------------------------
__global__ __launch_bounds__(256) void prep_kernel(const float* __restrict__ W0,
                                                   const float* __restrict__ W1,
                                                   unsigned short* __restrict__ W0t,
                                                   unsigned short* __restrict__ W1t,
                                                   int* __restrict__ deg) {
    const int i = blockIdx.x * 256 + threadIdx.x;
    if (i < 512 * 128) {
        const int k = i / 128, c = i % 128;
        W0t[c * 512 + k] = f2bf(W0[i]);
    }
    const int j = i - 512 * 128;
    if (j >= 0 && j < 128 * 64) {
        const int k = j / 64, c = j % 64;
        W1t[c * 128 + k] = f2bf(W1[j]);
    }
    const int z = i - (512 * 128 + 128 * 64);
    if (z >= 0 && z < N_NODES) deg[z] = 0;
}

// ---------------------------------------------------------------------------
// Pipelined MFMA GEMM: C_bf16[N,M] = A_f32[N,K] @ W (Wt[M][K] bf16).
// 4 waves (2m x 2n), tile 64 x M, BK=32. Depth-2 prefetch in NAMED regs;
// double-buffered LDS; raw barriers.
// ---------------------------------------------------------------------------
template<int K, int M>
__global__ __launch_bounds__(256) void mfma_gemm_kernel(const float* __restrict__ A,
                                                        const unsigned short* __restrict__ Wt,
                                                        unsigned short* __restrict__ C, int N) {
    constexpr int NSTEP = K / 32;
    constexpr int NFR   = M / 32;
    constexpr int NB    = M / 64;
    constexpr int LDT   = 40;       // LDS row stride (ushorts)

    __shared__ __align__(16) unsigned short As[2][64 * LDT];
    __shared__ __align__(16) unsigned short Bs[2][M * LDT];

    const int tid  = threadIdx.x;
    const int lane = tid & 63;
    const int wid  = tid >> 6;
    const int wm   = wid >> 1;
    const int wn   = wid & 1;
    const int brow = blockIdx.x * 64;

    const int ar0 = tid >> 3, akq = tid & 7;
    const int ar1 = ar0 + 32;
    const bool v0 = (brow + ar0) < N;
    const bool v1 = (brow + ar1) < N;
    const float* ap0 = A + (size_t)(brow + ar0) * K + akq * 4;
    const float* ap1 = A + (size_t)(brow + ar1) * K + akq * 4;
    const int br0 = tid >> 2, bkq = tid & 3;
    const unsigned short* bp0 = Wt + (size_t)br0 * K + bkq * 8;
    const unsigned short* bp1 = Wt + (size_t)(br0 + 64) * K + bkq * 8;

    float4 A0a, A0b, A1a, A1b;
    uint4  B0a, B0b, B1a, B1b;

    auto issue0 = [&](int t) {
        const int ko = t * 32;
        A0a = v0 ? *reinterpret_cast<const float4*>(ap0 + ko) : make_float4(0.f, 0.f, 0.f, 0.f);
        A0b = v1 ? *reinterpret_cast<const float4*>(ap1 + ko) : make_float4(0.f, 0.f, 0.f, 0.f);
        B0a = *reinterpret_cast<const uint4*>(bp0 + ko);
        if (NB == 2) B0b = *reinterpret_cast<const uint4*>(bp1 + ko);
    };
    auto issue1 = [&](int t) {
        const int ko = t * 32;
        A1a = v0 ? *reinterpret_cast<const float4*>(ap0 + ko) : make_float4(0.f, 0.f, 0.f, 0.f);
        A1b = v1 ? *reinterpret_cast<const float4*>(ap1 + ko) : make_float4(0.f, 0.f, 0.f, 0.f);
        B1a = *reinterpret_cast<const uint4*>(bp0 + ko);
        if (NB == 2) B1b = *reinterpret_cast<const uint4*>(bp1 + ko);
    };

    auto pack = [&](float4 v) -> uint2 {
        uint2 p;
        p.x = (unsigned int)f2bf(v.x) | ((unsigned int)f2bf(v.y) << 16);
        p.y = (unsigned int)f2bf(v.z) | ((unsigned int)f2bf(v.w) << 16);
        return p;
    };
    auto wlds0 = [&](int buf) {
        *reinterpret_cast<uint2*>(&As[buf][ar0 * LDT + akq * 4]) = pack(A0a);
        *reinterpret_cast<uint2*>(&As[buf][ar1 * LDT + akq * 4]) = pack(A0b);
        *reinterpret_cast<uint4*>(&Bs[buf][br0 * LDT + bkq * 8]) = B0a;
        if (NB == 2) *reinterpret_cast<uint4*>(&Bs[buf][(br0 + 64) * LDT + bkq * 8]) = B0b;
    };
    auto wlds1 = [&](int buf) {
        *reinterpret_cast<uint2*>(&As[buf][ar0 * LDT + akq * 4]) = pack(A1a);
        *reinterpret_cast<uint2*>(&As[buf][ar1 * LDT + akq * 4]) = pack(A1b);
        *reinterpret_cast<uint4*>(&Bs[buf][br0 * LDT + bkq * 8]) = B1a;
        if (NB == 2) *reinterpret_cast<uint4*>(&Bs[buf][(br0 + 64) * LDT + bkq * 8]) = B1b;
    };

    f32x4 acc[2][NFR];
#pragma unroll
    for (int m = 0; m < 2; ++m)
#pragma unroll
        for (int n = 0; n < NFR; ++n) acc[m][n] = (f32x4){0.f, 0.f, 0.f, 0.f};

    const int afo = (wm * 32 + (lane & 15)) * LDT + (lane >> 4) * 8;
    const int bfo = (wn * (M / 2) + (lane & 15)) * LDT + (lane >> 4) * 8;

    auto step = [&](int buf) {
        bf16x8 af[2], bfr[NFR];
#pragma unroll
        for (int m = 0; m < 2; ++m)
            af[m] = *reinterpret_cast<const bf16x8*>(&As[buf][afo + m * 16 * LDT]);
#pragma unroll
        for (int n = 0; n < NFR; ++n)
            bfr[n] = *reinterpret_cast<const bf16x8*>(&Bs[buf][bfo + n * 16 * LDT]);
#pragma unroll
        for (int m = 0; m < 2; ++m)
#pragma unroll
            for (int n = 0; n < NFR; ++n)
                acc[m][n] = __builtin_amdgcn_mfma_f32_16x16x32_bf16(af[m], bfr[n], acc[m][n], 0, 0, 0);
    };

    issue0(0);
    issue1(1);
    wlds0(0);
    block_barrier();

#pragma unroll
    for (int i = 0; i < NSTEP / 2; ++i) {
        const int t = 2 * i;
        if (t + 2 < NSTEP) issue0(t + 2);
        step(0);
        wlds1(1);
        block_barrier();
        if (t + 3 < NSTEP) issue1(t + 3);
        step(1);
        if (t + 2 < NSTEP) wlds0(0);
        block_barrier();
    }

    const int rb = brow + wm * 32 + ((lane >> 4) * 4);
    const int cb = wn * (M / 2) + (lane & 15);
#pragma unroll
    for (int m = 0; m < 2; ++m)
#pragma unroll
        for (int n = 0; n < NFR; ++n)
#pragma unroll
            for (int j = 0; j < 4; ++j) {
                const int r = rb + m * 16 + j;
                if (r < N) C[(size_t)r * M + cb + n * 16] = f2bf(acc[m][n][j]);
            }
}

// ---------------------------------------------------------------------------
// LDS-free GEMM2: sup1_bf16[N,64] = h_bf16[N,128] @ W1 (Wt[64][128] bf16).
// ---------------------------------------------------------------------------
__global__ __launch_bounds__(256) void gemm2_kernel(const unsigned short* __restrict__ Hb,
                                                    const unsigned short* __restrict__ Wt,
                                                    unsigned short* __restrict__ C) {
    const int gw = (blockIdx.x * 256 + threadIdx.x) >> 6;
    if (gw >= N_NODES / 16) return;
    const int lane = threadIdx.x & 63;
    const int rlo = lane & 15, khi = lane >> 4;
    const int rb = gw * 16;

    const unsigned short* wp = Wt + (size_t)rlo * 128 + khi * 8;
    bf16x8 b[4][4];
#pragma unroll
    for (int n = 0; n < 4; ++n)
#pragma unroll
        for (int t = 0; t < 4; ++t)
            b[n][t] = *reinterpret_cast<const bf16x8*>(wp + (size_t)n * 16 * 128 + t * 32);

    f32x4 acc[4];
#pragma unroll
    for (int n = 0; n < 4; ++n) acc[n] = (f32x4){0.f, 0.f, 0.f, 0.f};

    const unsigned short* hp = Hb + (size_t)(rb + rlo) * 128 + khi * 8;
#pragma unroll
    for (int t = 0; t < 4; ++t) {
        const bf16x8 af = *reinterpret_cast<const bf16x8*>(hp + t * 32);
#pragma unroll
        for (int n = 0; n < 4; ++n)
            acc[n] = __builtin_amdgcn_mfma_f32_16x16x32_bf16(af, b[n][t], acc[n], 0, 0, 0);
    }

#pragma unroll
    for (int n = 0; n < 4; ++n)
#pragma unroll
        for (int j = 0; j < 4; ++j)
            C[(size_t)(rb + khi * 4 + j) * 64 + n * 16 + rlo] = f2bf(acc[n][j]);
}

// ---------------------------------------------------------------------------
// CSR construction
// ---------------------------------------------------------------------------
__global__ __launch_bounds__(256) void hist_kernel(const int4* __restrict__ rows4,
                                                   int* __restrict__ deg) {
    const int e4 = blockIdx.x * 256 + threadIdx.x;
    if (e4 < N_EDGES / 4) {
        const int4 r = rows4[e4];
        atomicAdd(&deg[r.x], 1);
        atomicAdd(&deg[r.y], 1);
        atomicAdd(&deg[r.z], 1);
        atomicAdd(&deg[r.w], 1);
    }
}

__global__ __launch_bounds__(256) void sum_blocks_kernel(const int* __restrict__ deg,
                                                         int* __restrict__ bsum) {
    __shared__ int red[256];
    const int tid = threadIdx.x;
    const int i4  = blockIdx.x * 1024 + tid * 4;
    int s = 0;
#pragma unroll
    for (int k = 0; k < 4; ++k) {
        const int i = i4 + k;
        if (i < N_NODES) s += deg[i];
    }
    red[tid] = s;
    __syncthreads();
#pragma unroll
    for (int off = 128; off > 0; off >>= 1) {
        if (tid < off) red[tid] += red[tid + off];
        __syncthreads();
    }
    if (tid == 0) bsum[blockIdx.x] = red[0];
}

// Per-block scan + inline scan of block sums; emits row_ptr and the
// per-bucket cursors (bucket = 128 rows, base offset = row_ptr[128b]).
__global__ __launch_bounds__(256) void scan_final_kernel(const int* __restrict__ deg,
                                                         const int* __restrict__ bsum,
                                                         int nblk,
                                                         int* __restrict__ row_ptr,
                                                         int* __restrict__ bcursor) {
    __shared__ int bsh[256];
    __shared__ int tsum[256];
    const int tid = threadIdx.x;

    bsh[tid] = (tid < nblk) ? bsum[tid] : 0;
    __syncthreads();
    for (int off = 1; off < 256; off <<= 1) {
        const int t = (tid >= off) ? bsh[tid - off] : 0;
        __syncthreads();
        bsh[tid] += t;
        __syncthreads();
    }
    const int boff = (blockIdx.x == 0) ? 0 : bsh[blockIdx.x - 1];

    const int base_i = blockIdx.x * 1024 + tid * 4;
    int d[4];
#pragma unroll
    for (int k = 0; k < 4; ++k) {
        const int i = base_i + k;
        d[k] = (i < N_NODES) ? deg[i] : 0;
    }
    const int s = d[0] + d[1] + d[2] + d[3];
    tsum[tid] = s;
    __syncthreads();
    for (int off = 1; off < 256; off <<= 1) {
        const int t = (tid >= off) ? tsum[tid - off] : 0;
        __syncthreads();
        tsum[tid] += t;
        __syncthreads();
    }
    int p = tsum[tid] - s + boff;
#pragma unroll
    for (int k = 0; k < 4; ++k) {
        const int i = base_i + k;
        if (i < N_NODES) {
            row_ptr[i] = p;
            if ((i & 127) == 0) bcursor[i >> 7] = p;
            if (i == N_NODES - 1) row_ptr[N_NODES] = p + d[k];
        }
        p += d[k];
    }
}

// Pass A: append edges into their bucket region (sequential frontier per
// bucket -> L2-merged writes). Payload: {col | (row&127)<<17, val_bits}.
__global__ __launch_bounds__(256) void scatter_bucket_kernel(const int* __restrict__ rows,
                                                             const int* __restrict__ cols,
                                                             const float* __restrict__ vals,
                                                             int* __restrict__ bcursor,
                                                             int2* __restrict__ tmp) {
    const int e = blockIdx.x * 256 + threadIdx.x;
    const int r = rows[e];
    const int pos = atomicAdd(&bcursor[r >> 7], 1);
    tmp[pos] = make_int2(cols[e] | ((r & 127) << 17), __float_as_int(vals[e]));
}

// Pass B: one block per bucket; LDS cursors (no global atomics); writes land
// in the bucket's ~16KB output window (L2-local).
__global__ __launch_bounds__(256) void scatter_final_kernel(const int* __restrict__ row_ptr,
                                                            const int2* __restrict__ tmp,
                                                            int2* __restrict__ meta) {
    __shared__ int cur[128];
    const int b   = blockIdx.x;
    const int tid = threadIdx.x;
    const int rbase = b << 7;
    if (tid < 128) {
        const int r = rbase + tid;
        cur[tid] = (r < N_NODES) ? row_ptr[r] : 0;
    }
    __syncthreads();

    const int start = row_ptr[min(rbase, N_NODES)];
    const int end   = row_ptr[min(rbase + 128, N_NODES)];
    for (int j = start + tid; j < end; j += 256) {
        const int2 w  = tmp[j];
        const int  rl = ((unsigned int)w.x) >> 17;
        const int  pos = atomicAdd(&cur[rl], 1);
        meta[pos] = make_int2(w.x & 0x1FFFF, w.y);
    }
}

// ---------------------------------------------------------------------------
// Atomic-free SpMM, one wave per row, NG edge-parallel groups, UN-deep unroll.
// ---------------------------------------------------------------------------
template<int DIM, bool RELU_BF16_OUT>
__global__ __launch_bounds__(256) void spmm_kernel(const int* __restrict__ row_ptr,
                                                   const int2* __restrict__ meta,
                                                   const unsigned short* __restrict__ sup,
                                                   const float* __restrict__ bias,
                                                   void* __restrict__ aggv) {
    const int wv = (blockIdx.x * 256 + threadIdx.x) >> 6;  // row id
    if (wv >= N_NODES) return;
    const int lane = threadIdx.x & 63;

    constexpr int GL = DIM / 8;              // lanes per group (16 / 8)
    constexpr int NG = 64 / GL;              // edge-parallel groups (4 / 8)
    constexpr int UN = (DIM == 128) ? 4 : 2; // unroll depth
    const int grp = lane / GL;
    const int sub = lane % GL;

    const int start = row_ptr[wv];
    const int end   = row_ptr[wv + 1];

    float a[8] = {0.f, 0.f, 0.f, 0.f, 0.f, 0.f, 0.f, 0.f};

    int j = start + grp;
    while (j + (UN - 1) * NG < end) {
        int2 e[UN];
#pragma unroll
        for (int u = 0; u < UN; ++u) e[u] = meta[j + u * NG];
        bf16x8 s[UN];
#pragma unroll
        for (int u = 0; u < UN; ++u)
            s[u] = *reinterpret_cast<const bf16x8*>(sup + (size_t)e[u].x * DIM + sub * 8);
#pragma unroll
        for (int u = 0; u < UN; ++u) {
            const float v = __int_as_float(e[u].y);
#pragma unroll
            for (int d = 0; d < 8; ++d)
                a[d] = fmaf(v, bfu2f((unsigned short)s[u][d]), a[d]);
        }
        j += UN * NG;
    }
    for (; j < end; j += NG) {
        const int2 e = meta[j];
        const bf16x8 s = *reinterpret_cast<const bf16x8*>(sup + (size_t)e.x * DIM + sub * 8);
        const float v = __int_as_float(e.y);
#pragma unroll
        for (int d = 0; d < 8; ++d)
            a[d] = fmaf(v, bfu2f((unsigned short)s[d]), a[d]);
    }

#pragma unroll
    for (int d = 0; d < 8; ++d) {
        if (GL == 8) a[d] += __shfl_xor(a[d], 8);
        a[d] += __shfl_xor(a[d], 16);
        a[d] += __shfl_xor(a[d], 32);
    }

    if (lane < GL) {
        const float4 b0 = *reinterpret_cast<const float4*>(bias + sub * 8);
        const float4 b1 = *reinterpret_cast<const float4*>(bias + sub * 8 + 4);
        float o[8];
        o[0] = a[0] + b0.x; o[1] = a[1] + b0.y; o[2] = a[2] + b0.z; o[3] = a[3] + b0.w;
        o[4] = a[4] + b1.x; o[5] = a[5] + b1.y; o[6] = a[6] + b1.z; o[7] = a[7] + b1.w;
        if (RELU_BF16_OUT) {
            unsigned short* h = (unsigned short*)aggv;
            bf16x8 r;
#pragma unroll
            for (int d = 0; d < 8; ++d) r[d] = (short)f2bf(fmaxf(o[d], 0.f));
            *reinterpret_cast<bf16x8*>(h + (size_t)wv * DIM + sub * 8) = r;
        } else {
            float* og = (float*)aggv;
            float* dst = og + (size_t)wv * DIM + sub * 8;
            *reinterpret_cast<float4*>(dst)     = make_float4(o[0], o[1], o[2], o[3]);
            *reinterpret_cast<float4*>(dst + 4) = make_float4(o[4], o[5], o[6], o[7]);
        }
    }
}

// ---------------------------------------------------------------------------
extern "C" void kernel_launch(void* const* d_in, const int* in_sizes, int n_in,
                              void* d_out, int out_size, void* d_ws, size_t ws_size,
                              hipStream_t stream) {
    const float* x    = (const float*)d_in[0];
    const int*   rows = (const int*)d_in[1];
    const int*   cols = (const int*)d_in[2];
    const float* vals = (const float*)d_in[3];
    const float* W0   = (const float*)d_in[4];
    const float* b0   = (const float*)d_in[5];
    const float* W1   = (const float*)d_in[6];
    const float* b1   = (const float*)d_in[7];
    float*       out  = (float*)d_out;

    // Workspace carve (all chunks 16B-multiple)
    char* p = (char*)d_ws;
    unsigned short* sup0 = (unsigned short*)p;  p += (size_t)N_NODES * 128 * 2;  // 25.6 MB
    unsigned short* h    = (unsigned short*)p;  p += (size_t)N_NODES * 128 * 2;  // 25.6 MB
    unsigned short* sup1 = (unsigned short*)p;  p += (size_t)N_NODES * 64 * 2;   // 12.8 MB
    unsigned short* W0t  = (unsigned short*)p;  p += (size_t)512 * 128 * 2;
    unsigned short* W1t  = (unsigned short*)p;  p += (size_t)128 * 64 * 2;
    int*   deg      = (int*)p;                  p += (size_t)N_NODES * 4;
    int*   row_ptr  = (int*)p;                  p += (size_t)(N_NODES + 4) * 4;
    int*   bsum     = (int*)p;                  p += 256 * 4;
    int*   bcursor  = (int*)p;                  p += (size_t)((NBUCK + 3) / 4) * 16;
    int2*  meta     = (int2*)p;                 p += (size_t)N_EDGES * 8;        // 12.8 MB
    int2*  tmp      = (int2*)p;                 p += (size_t)N_EDGES * 8;        // 12.8 MB

    constexpr int SCAN_BLOCKS = (N_NODES + 1023) / 1024;   // 98
    const int prep_blocks = (512 * 128 + 128 * 64 + N_NODES + 255) / 256;  // 679
    const int hist_blocks = (N_EDGES / 4 + 255) / 256;      // 1563
    const int edge_blocks = N_EDGES / 256;                  // 6250
    const int gemm_blocks = (N_NODES + 63) / 64;            // 1563
    const int spmm_blocks = (N_NODES * 64 + 255) / 256;     // 25000

    // ---- prep (W converts + deg zero) ----
    prep_kernel<<<prep_blocks, 256, 0, stream>>>(W0, W1, W0t, W1t, deg);

    // ---- CSR build (2-pass bucketed scatter) ----
    hist_kernel<<<hist_blocks, 256, 0, stream>>>((const int4*)rows, deg);
    sum_blocks_kernel<<<SCAN_BLOCKS, 256, 0, stream>>>(deg, bsum);
    scan_final_kernel<<<SCAN_BLOCKS, 256, 0, stream>>>(deg, bsum, SCAN_BLOCKS, row_ptr, bcursor);
    scatter_bucket_kernel<<<edge_blocks, 256, 0, stream>>>(rows, cols, vals, bcursor, tmp);
    scatter_final_kernel<<<NBUCK, 256, 0, stream>>>(row_ptr, tmp, meta);

    // ---- Layer 0 ----
    mfma_gemm_kernel<512, 128><<<gemm_blocks, 256, 0, stream>>>(x, W0t, sup0, N_NODES);
    spmm_kernel<128, true><<<spmm_blocks, 256, 0, stream>>>(row_ptr, meta, sup0, b0, h);

    // ---- Layer 1 ----
    gemm2_kernel<<<gemm_blocks, 256, 0, stream>>>(h, W1t, sup1);
    spmm_kernel<64, false><<<spmm_blocks, 256, 0, stream>>>(row_ptr, meta, sup1, b1, out);
}

// Round 9
// 321.430 us; speedup vs baseline: 2.0232x; 2.0232x over previous
//
#include <hip/hip_runtime.h>

#define N_NODES 100000
#define N_EDGES 1600000
#define NBUCK   ((N_NODES + 127) / 128)   // 782 buckets of 128 rows
// IN_DIM=512, HID_DIM=128, OUT_DIM=64

typedef __attribute__((ext_vector_type(8))) short bf16x8;
typedef __attribute__((ext_vector_type(4))) float f32x4;

__device__ __forceinline__ unsigned short f2bf(float f) {
    unsigned int u = __builtin_bit_cast(unsigned int, f);
    u = (u + 0x7FFFu + ((u >> 16) & 1u)) >> 16;   // RNE
    return (unsigned short)u;
}
__device__ __forceinline__ float bfu2f(unsigned short u) {
    return __builtin_bit_cast(float, (unsigned int)u << 16);
}

// Raw barrier: waits LDS ops only — global prefetch loads stay in flight.
__device__ __forceinline__ void block_barrier() {
    asm volatile("s_waitcnt lgkmcnt(0)" ::: "memory");
    __builtin_amdgcn_sched_barrier(0);
    __builtin_amdgcn_s_barrier();
    __builtin_amdgcn_sched_barrier(0);
}

// ---------------------------------------------------------------------------
// prep: W0[512][128]->W0t[128][512] bf16, W1[128][64]->W1t[64][128] bf16,
// deg[] = 0.  One launch.
// ---------------------------------------------------------------------------
__global__ __launch_bounds__(256) void prep_kernel(const float* __restrict__ W0,
                                                   const float* __restrict__ W1,
                                                   unsigned short* __restrict__ W0t,
                                                   unsigned short* __restrict__ W1t,
                                                   int* __restrict__ deg) {
    const int i = blockIdx.x * 256 + threadIdx.x;
    if (i < 512 * 128) {
        const int k = i / 128, c = i % 128;
        W0t[c * 512 + k] = f2bf(W0[i]);
    }
    const int j = i - 512 * 128;
    if (j >= 0 && j < 128 * 64) {
        const int k = j / 64, c = j % 64;
        W1t[c * 128 + k] = f2bf(W1[j]);
    }
    const int z = i - (512 * 128 + 128 * 64);
    if (z >= 0 && z < N_NODES) deg[z] = 0;
}

// ---------------------------------------------------------------------------
// Pipelined MFMA GEMM: C_bf16[N,M] = A_f32[N,K] @ W (Wt[M][K] bf16).
// 4 waves (2m x 2n), tile 64 x M, BK=32. Depth-2 prefetch in NAMED regs;
// double-buffered LDS; raw barriers.
// ---------------------------------------------------------------------------
template<int K, int M>
__global__ __launch_bounds__(256) void mfma_gemm_kernel(const float* __restrict__ A,
                                                        const unsigned short* __restrict__ Wt,
                                                        unsigned short* __restrict__ C, int N) {
    constexpr int NSTEP = K / 32;
    constexpr int NFR   = M / 32;
    constexpr int NB    = M / 64;
    constexpr int LDT   = 40;       // LDS row stride (ushorts)

    __shared__ __align__(16) unsigned short As[2][64 * LDT];
    __shared__ __align__(16) unsigned short Bs[2][M * LDT];

    const int tid  = threadIdx.x;
    const int lane = tid & 63;
    const int wid  = tid >> 6;
    const int wm   = wid >> 1;
    const int wn   = wid & 1;
    const int brow = blockIdx.x * 64;

    const int ar0 = tid >> 3, akq = tid & 7;
    const int ar1 = ar0 + 32;
    const bool v0 = (brow + ar0) < N;
    const bool v1 = (brow + ar1) < N;
    const float* ap0 = A + (size_t)(brow + ar0) * K + akq * 4;
    const float* ap1 = A + (size_t)(brow + ar1) * K + akq * 4;
    const int br0 = tid >> 2, bkq = tid & 3;
    const unsigned short* bp0 = Wt + (size_t)br0 * K + bkq * 8;
    const unsigned short* bp1 = Wt + (size_t)(br0 + 64) * K + bkq * 8;

    float4 A0a, A0b, A1a, A1b;
    uint4  B0a, B0b, B1a, B1b;

    auto issue0 = [&](int t) {
        const int ko = t * 32;
        A0a = v0 ? *reinterpret_cast<const float4*>(ap0 + ko) : make_float4(0.f, 0.f, 0.f, 0.f);
        A0b = v1 ? *reinterpret_cast<const float4*>(ap1 + ko) : make_float4(0.f, 0.f, 0.f, 0.f);
        B0a = *reinterpret_cast<const uint4*>(bp0 + ko);
        if (NB == 2) B0b = *reinterpret_cast<const uint4*>(bp1 + ko);
    };
    auto issue1 = [&](int t) {
        const int ko = t * 32;
        A1a = v0 ? *reinterpret_cast<const float4*>(ap0 + ko) : make_float4(0.f, 0.f, 0.f, 0.f);
        A1b = v1 ? *reinterpret_cast<const float4*>(ap1 + ko) : make_float4(0.f, 0.f, 0.f, 0.f);
        B1a = *reinterpret_cast<const uint4*>(bp0 + ko);
        if (NB == 2) B1b = *reinterpret_cast<const uint4*>(bp1 + ko);
    };

    auto pack = [&](float4 v) -> uint2 {
        uint2 p;
        p.x = (unsigned int)f2bf(v.x) | ((unsigned int)f2bf(v.y) << 16);
        p.y = (unsigned int)f2bf(v.z) | ((unsigned int)f2bf(v.w) << 16);
        return p;
    };
    auto wlds0 = [&](int buf) {
        *reinterpret_cast<uint2*>(&As[buf][ar0 * LDT + akq * 4]) = pack(A0a);
        *reinterpret_cast<uint2*>(&As[buf][ar1 * LDT + akq * 4]) = pack(A0b);
        *reinterpret_cast<uint4*>(&Bs[buf][br0 * LDT + bkq * 8]) = B0a;
        if (NB == 2) *reinterpret_cast<uint4*>(&Bs[buf][(br0 + 64) * LDT + bkq * 8]) = B0b;
    };
    auto wlds1 = [&](int buf) {
        *reinterpret_cast<uint2*>(&As[buf][ar0 * LDT + akq * 4]) = pack(A1a);
        *reinterpret_cast<uint2*>(&As[buf][ar1 * LDT + akq * 4]) = pack(A1b);
        *reinterpret_cast<uint4*>(&Bs[buf][br0 * LDT + bkq * 8]) = B1a;
        if (NB == 2) *reinterpret_cast<uint4*>(&Bs[buf][(br0 + 64) * LDT + bkq * 8]) = B1b;
    };

    f32x4 acc[2][NFR];
#pragma unroll
    for (int m = 0; m < 2; ++m)
#pragma unroll
        for (int n = 0; n < NFR; ++n) acc[m][n] = (f32x4){0.f, 0.f, 0.f, 0.f};

    const int afo = (wm * 32 + (lane & 15)) * LDT + (lane >> 4) * 8;
    const int bfo = (wn * (M / 2) + (lane & 15)) * LDT + (lane >> 4) * 8;

    auto step = [&](int buf) {
        bf16x8 af[2], bfr[NFR];
#pragma unroll
        for (int m = 0; m < 2; ++m)
            af[m] = *reinterpret_cast<const bf16x8*>(&As[buf][afo + m * 16 * LDT]);
#pragma unroll
        for (int n = 0; n < NFR; ++n)
            bfr[n] = *reinterpret_cast<const bf16x8*>(&Bs[buf][bfo + n * 16 * LDT]);
#pragma unroll
        for (int m = 0; m < 2; ++m)
#pragma unroll
            for (int n = 0; n < NFR; ++n)
                acc[m][n] = __builtin_amdgcn_mfma_f32_16x16x32_bf16(af[m], bfr[n], acc[m][n], 0, 0, 0);
    };

    issue0(0);
    issue1(1);
    wlds0(0);
    block_barrier();

#pragma unroll
    for (int i = 0; i < NSTEP / 2; ++i) {
        const int t = 2 * i;
        if (t + 2 < NSTEP) issue0(t + 2);
        step(0);
        wlds1(1);
        block_barrier();
        if (t + 3 < NSTEP) issue1(t + 3);
        step(1);
        if (t + 2 < NSTEP) wlds0(0);
        block_barrier();
    }

    const int rb = brow + wm * 32 + ((lane >> 4) * 4);
    const int cb = wn * (M / 2) + (lane & 15);
#pragma unroll
    for (int m = 0; m < 2; ++m)
#pragma unroll
        for (int n = 0; n < NFR; ++n)
#pragma unroll
            for (int j = 0; j < 4; ++j) {
                const int r = rb + m * 16 + j;
                if (r < N) C[(size_t)r * M + cb + n * 16] = f2bf(acc[m][n][j]);
            }
}

// ---------------------------------------------------------------------------
// LDS-free GEMM2: sup1_bf16[N,64] = h_bf16[N,128] @ W1 (Wt[64][128] bf16).
// ---------------------------------------------------------------------------
__global__ __launch_bounds__(256) void gemm2_kernel(const unsigned short* __restrict__ Hb,
                                                    const unsigned short* __restrict__ Wt,
                                                    unsigned short* __restrict__ C) {
    const int gw = (blockIdx.x * 256 + threadIdx.x) >> 6;
    if (gw >= N_NODES / 16) return;
    const int lane = threadIdx.x & 63;
    const int rlo = lane & 15, khi = lane >> 4;
    const int rb = gw * 16;

    const unsigned short* wp = Wt + (size_t)rlo * 128 + khi * 8;
    bf16x8 b[4][4];
#pragma unroll
    for (int n = 0; n < 4; ++n)
#pragma unroll
        for (int t = 0; t < 4; ++t)
            b[n][t] = *reinterpret_cast<const bf16x8*>(wp + (size_t)n * 16 * 128 + t * 32);

    f32x4 acc[4];
#pragma unroll
    for (int n = 0; n < 4; ++n) acc[n] = (f32x4){0.f, 0.f, 0.f, 0.f};

    const unsigned short* hp = Hb + (size_t)(rb + rlo) * 128 + khi * 8;
#pragma unroll
    for (int t = 0; t < 4; ++t) {
        const bf16x8 af = *reinterpret_cast<const bf16x8*>(hp + t * 32);
#pragma unroll
        for (int n = 0; n < 4; ++n)
            acc[n] = __builtin_amdgcn_mfma_f32_16x16x32_bf16(af, b[n][t], acc[n], 0, 0, 0);
    }

#pragma unroll
    for (int n = 0; n < 4; ++n)
#pragma unroll
        for (int j = 0; j < 4; ++j)
            C[(size_t)(rb + khi * 4 + j) * 64 + n * 16 + rlo] = f2bf(acc[n][j]);
}

// ---------------------------------------------------------------------------
// CSR construction
// ---------------------------------------------------------------------------
__global__ __launch_bounds__(256) void hist_kernel(const int4* __restrict__ rows4,
                                                   int* __restrict__ deg) {
    const int e4 = blockIdx.x * 256 + threadIdx.x;
    if (e4 < N_EDGES / 4) {
        const int4 r = rows4[e4];
        atomicAdd(&deg[r.x], 1);
        atomicAdd(&deg[r.y], 1);
        atomicAdd(&deg[r.z], 1);
        atomicAdd(&deg[r.w], 1);
    }
}

__global__ __launch_bounds__(256) void sum_blocks_kernel(const int* __restrict__ deg,
                                                         int* __restrict__ bsum) {
    __shared__ int red[256];
    const int tid = threadIdx.x;
    const int i4  = blockIdx.x * 1024 + tid * 4;
    int s = 0;
#pragma unroll
    for (int k = 0; k < 4; ++k) {
        const int i = i4 + k;
        if (i < N_NODES) s += deg[i];
    }
    red[tid] = s;
    __syncthreads();
#pragma unroll
    for (int off = 128; off > 0; off >>= 1) {
        if (tid < off) red[tid] += red[tid + off];
        __syncthreads();
    }
    if (tid == 0) bsum[blockIdx.x] = red[0];
}

// Per-block scan + inline scan of block sums; emits row_ptr and the
// per-bucket cursors (bucket = 128 rows, base offset = row_ptr[128b]).
__global__ __launch_bounds__(256) void scan_final_kernel(const int* __restrict__ deg,
                                                         const int* __restrict__ bsum,
                                                         int nblk,
                                                         int* __restrict__ row_ptr,
                                                         int* __restrict__ bcursor) {
    __shared__ int bsh[256];
    __shared__ int tsum[256];
    const int tid = threadIdx.x;

    bsh[tid] = (tid < nblk) ? bsum[tid] : 0;
    __syncthreads();
    for (int off = 1; off < 256; off <<= 1) {
        const int t = (tid >= off) ? bsh[tid - off] : 0;
        __syncthreads();
        bsh[tid] += t;
        __syncthreads();
    }
    const int boff = (blockIdx.x == 0) ? 0 : bsh[blockIdx.x - 1];

    const int base_i = blockIdx.x * 1024 + tid * 4;
    int d[4];
#pragma unroll
    for (int k = 0; k < 4; ++k) {
        const int i = base_i + k;
        d[k] = (i < N_NODES) ? deg[i] : 0;
    }
    const int s = d[0] + d[1] + d[2] + d[3];
    tsum[tid] = s;
    __syncthreads();
    for (int off = 1; off < 256; off <<= 1) {
        const int t = (tid >= off) ? tsum[tid - off] : 0;
        __syncthreads();
        tsum[tid] += t;
        __syncthreads();
    }
    int p = tsum[tid] - s + boff;
#pragma unroll
    for (int k = 0; k < 4; ++k) {
        const int i = base_i + k;
        if (i < N_NODES) {
            row_ptr[i] = p;
            if ((i & 127) == 0) bcursor[i >> 7] = p;
            if (i == N_NODES - 1) row_ptr[N_NODES] = p + d[k];
        }
        p += d[k];
    }
}

// Pass A (block-aggregated): each block histograms its 4096 edges over the
// 782 buckets in LDS, reserves per-bucket space with ONE global atomic per
// (block, nonzero bucket), then appends edges via LDS cursors. Kills the
// 782-hot-counter contention (r8) AND most sector write amplification (r7).
#define SCAT_CH 4096
__global__ __launch_bounds__(256) void scatter_bucket_kernel(const int* __restrict__ rows,
                                                             const int* __restrict__ cols,
                                                             const float* __restrict__ vals,
                                                             int* __restrict__ bcursor,
                                                             int2* __restrict__ tmp) {
    __shared__ int hist[NBUCK];   // counts, then global-base cursors
    const int tid = threadIdx.x;
    const int e0  = blockIdx.x * SCAT_CH;

    for (int b = tid; b < NBUCK; b += 256) hist[b] = 0;
    __syncthreads();

    // phase 1: block-local histogram
#pragma unroll
    for (int i = 0; i < SCAT_CH / 256; ++i) {
        const int e = e0 + i * 256 + tid;
        if (e < N_EDGES) atomicAdd(&hist[rows[e] >> 7], 1);
    }
    __syncthreads();

    // phase 2: reserve global region per bucket (one atomic per nonzero bucket)
    for (int b = tid; b < NBUCK; b += 256) {
        const int hcnt = hist[b];
        hist[b] = (hcnt > 0) ? atomicAdd(&bcursor[b], hcnt) : 0;
    }
    __syncthreads();

    // phase 3: append via LDS cursors (edge data L2-hot from phase 1)
#pragma unroll
    for (int i = 0; i < SCAT_CH / 256; ++i) {
        const int e = e0 + i * 256 + tid;
        if (e < N_EDGES) {
            const int r   = rows[e];
            const int pos = atomicAdd(&hist[r >> 7], 1);
            tmp[pos] = make_int2(cols[e] | ((r & 127) << 17), __float_as_int(vals[e]));
        }
    }
}

// Pass B: one block per bucket; LDS cursors; writes land in the bucket's
// ~16KB output window (single block -> single XCD -> L2-merged).
__global__ __launch_bounds__(256) void scatter_final_kernel(const int* __restrict__ row_ptr,
                                                            const int2* __restrict__ tmp,
                                                            int2* __restrict__ meta) {
    __shared__ int cur[128];
    const int b   = blockIdx.x;
    const int tid = threadIdx.x;
    const int rbase = b << 7;
    if (tid < 128) {
        const int r = rbase + tid;
        cur[tid] = (r < N_NODES) ? row_ptr[r] : 0;
    }
    __syncthreads();

    const int start = row_ptr[min(rbase, N_NODES)];
    const int end   = row_ptr[min(rbase + 128, N_NODES)];
    for (int j = start + tid; j < end; j += 256) {
        const int2 w  = tmp[j];
        const int  rl = ((unsigned int)w.x) >> 17;
        const int  pos = atomicAdd(&cur[rl], 1);
        meta[pos] = make_int2(w.x & 0x1FFFF, w.y);
    }
}

// ---------------------------------------------------------------------------
// Atomic-free SpMM, one wave per row, NG edge-parallel groups, UN-deep unroll.
// ---------------------------------------------------------------------------
template<int DIM, bool RELU_BF16_OUT>
__global__ __launch_bounds__(256) void spmm_kernel(const int* __restrict__ row_ptr,
                                                   const int2* __restrict__ meta,
                                                   const unsigned short* __restrict__ sup,
                                                   const float* __restrict__ bias,
                                                   void* __restrict__ aggv) {
    const int wv = (blockIdx.x * 256 + threadIdx.x) >> 6;  // row id
    if (wv >= N_NODES) return;
    const int lane = threadIdx.x & 63;

    constexpr int GL = DIM / 8;              // lanes per group (16 / 8)
    constexpr int NG = 64 / GL;              // edge-parallel groups (4 / 8)
    constexpr int UN = (DIM == 128) ? 4 : 2; // unroll depth
    const int grp = lane / GL;
    const int sub = lane % GL;

    const int start = row_ptr[wv];
    const int end   = row_ptr[wv + 1];

    float a[8] = {0.f, 0.f, 0.f, 0.f, 0.f, 0.f, 0.f, 0.f};

    int j = start + grp;
    while (j + (UN - 1) * NG < end) {
        int2 e[UN];
#pragma unroll
        for (int u = 0; u < UN; ++u) e[u] = meta[j + u * NG];
        bf16x8 s[UN];
#pragma unroll
        for (int u = 0; u < UN; ++u)
            s[u] = *reinterpret_cast<const bf16x8*>(sup + (size_t)e[u].x * DIM + sub * 8);
#pragma unroll
        for (int u = 0; u < UN; ++u) {
            const float v = __int_as_float(e[u].y);
#pragma unroll
            for (int d = 0; d < 8; ++d)
                a[d] = fmaf(v, bfu2f((unsigned short)s[u][d]), a[d]);
        }
        j += UN * NG;
    }
    for (; j < end; j += NG) {
        const int2 e = meta[j];
        const bf16x8 s = *reinterpret_cast<const bf16x8*>(sup + (size_t)e.x * DIM + sub * 8);
        const float v = __int_as_float(e.y);
#pragma unroll
        for (int d = 0; d < 8; ++d)
            a[d] = fmaf(v, bfu2f((unsigned short)s[d]), a[d]);
    }

#pragma unroll
    for (int d = 0; d < 8; ++d) {
        if (GL == 8) a[d] += __shfl_xor(a[d], 8);
        a[d] += __shfl_xor(a[d], 16);
        a[d] += __shfl_xor(a[d], 32);
    }

    if (lane < GL) {
        const float4 b0 = *reinterpret_cast<const float4*>(bias + sub * 8);
        const float4 b1 = *reinterpret_cast<const float4*>(bias + sub * 8 + 4);
        float o[8];
        o[0] = a[0] + b0.x; o[1] = a[1] + b0.y; o[2] = a[2] + b0.z; o[3] = a[3] + b0.w;
        o[4] = a[4] + b1.x; o[5] = a[5] + b1.y; o[6] = a[6] + b1.z; o[7] = a[7] + b1.w;
        if (RELU_BF16_OUT) {
            unsigned short* h = (unsigned short*)aggv;
            bf16x8 r;
#pragma unroll
            for (int d = 0; d < 8; ++d) r[d] = (short)f2bf(fmaxf(o[d], 0.f));
            *reinterpret_cast<bf16x8*>(h + (size_t)wv * DIM + sub * 8) = r;
        } else {
            float* og = (float*)aggv;
            float* dst = og + (size_t)wv * DIM + sub * 8;
            *reinterpret_cast<float4*>(dst)     = make_float4(o[0], o[1], o[2], o[3]);
            *reinterpret_cast<float4*>(dst + 4) = make_float4(o[4], o[5], o[6], o[7]);
        }
    }
}

// ---------------------------------------------------------------------------
extern "C" void kernel_launch(void* const* d_in, const int* in_sizes, int n_in,
                              void* d_out, int out_size, void* d_ws, size_t ws_size,
                              hipStream_t stream) {
    const float* x    = (const float*)d_in[0];
    const int*   rows = (const int*)d_in[1];
    const int*   cols = (const int*)d_in[2];
    const float* vals = (const float*)d_in[3];
    const float* W0   = (const float*)d_in[4];
    const float* b0   = (const float*)d_in[5];
    const float* W1   = (const float*)d_in[6];
    const float* b1   = (const float*)d_in[7];
    float*       out  = (float*)d_out;

    // Workspace carve (all chunks 16B-multiple)
    char* p = (char*)d_ws;
    unsigned short* sup0 = (unsigned short*)p;  p += (size_t)N_NODES * 128 * 2;  // 25.6 MB
    unsigned short* h    = (unsigned short*)p;  p += (size_t)N_NODES * 128 * 2;  // 25.6 MB
    unsigned short* sup1 = (unsigned short*)p;  p += (size_t)N_NODES * 64 * 2;   // 12.8 MB
    unsigned short* W0t  = (unsigned short*)p;  p += (size_t)512 * 128 * 2;
    unsigned short* W1t  = (unsigned short*)p;  p += (size_t)128 * 64 * 2;
    int*   deg      = (int*)p;                  p += (size_t)N_NODES * 4;
    int*   row_ptr  = (int*)p;                  p += (size_t)(N_NODES + 4) * 4;
    int*   bsum     = (int*)p;                  p += 256 * 4;
    int*   bcursor  = (int*)p;                  p += (size_t)((NBUCK + 3) / 4) * 16;
    int2*  meta     = (int2*)p;                 p += (size_t)N_EDGES * 8;        // 12.8 MB
    int2*  tmp      = (int2*)p;                 p += (size_t)N_EDGES * 8;        // 12.8 MB

    constexpr int SCAN_BLOCKS = (N_NODES + 1023) / 1024;   // 98
    const int prep_blocks = (512 * 128 + 128 * 64 + N_NODES + 255) / 256;  // 679
    const int hist_blocks = (N_EDGES / 4 + 255) / 256;      // 1563
    const int scat_blocks = (N_EDGES + SCAT_CH - 1) / SCAT_CH;  // 391
    const int gemm_blocks = (N_NODES + 63) / 64;            // 1563
    const int spmm_blocks = (N_NODES * 64 + 255) / 256;     // 25000

    // ---- prep (W converts + deg zero) ----
    prep_kernel<<<prep_blocks, 256, 0, stream>>>(W0, W1, W0t, W1t, deg);

    // ---- CSR build (block-aggregated 2-pass bucketed scatter) ----
    hist_kernel<<<hist_blocks, 256, 0, stream>>>((const int4*)rows, deg);
    sum_blocks_kernel<<<SCAN_BLOCKS, 256, 0, stream>>>(deg, bsum);
    scan_final_kernel<<<SCAN_BLOCKS, 256, 0, stream>>>(deg, bsum, SCAN_BLOCKS, row_ptr, bcursor);
    scatter_bucket_kernel<<<scat_blocks, 256, 0, stream>>>(rows, cols, vals, bcursor, tmp);
    scatter_final_kernel<<<NBUCK, 256, 0, stream>>>(row_ptr, tmp, meta);

    // ---- Layer 0 ----
    mfma_gemm_kernel<512, 128><<<gemm_blocks, 256, 0, stream>>>(x, W0t, sup0, N_NODES);
    spmm_kernel<128, true><<<spmm_blocks, 256, 0, stream>>>(row_ptr, meta, sup0, b0, h);

    // ---- Layer 1 ----
    gemm2_kernel<<<gemm_blocks, 256, 0, stream>>>(h, W1t, sup1);
    spmm_kernel<64, false><<<spmm_blocks, 256, 0, stream>>>(row_ptr, meta, sup1, b1, out);
}